// Round 1
// baseline (60.277 us; speedup 1.0000x reference)
//
#include <hip/hip_runtime.h>
#include <math.h>

constexpr int Hn = 18, Wn = 18, HWn = 324;

__global__ __launch_bounds__(256) void psrw_kernel(
    const float* __restrict__ cv, const int* __restrict__ peak,
    float* __restrict__ out, int BC)
{
    int gtid = blockIdx.x * 256 + threadIdx.x;
    int wave = gtid >> 6;
    int lane = threadIdx.x & 63;
    if (wave >= BC) return;

    const float* row = cv + (size_t)wave * HWn;
    int py = peak[2 * wave];
    int px = peak[2 * wave + 1];

    // Row = 1296 B, 16B aligned, exactly 81 float4s: lane gets float4 #lane,
    // lanes 0..16 additionally get float4 #(64+lane).
    float4 v0 = reinterpret_cast<const float4*>(row)[lane];
    bool has2 = lane < 17;
    float4 v1 = make_float4(0.f, 0.f, 0.f, 0.f);
    if (has2) v1 = reinterpret_cast<const float4*>(row)[64 + lane];

    float c[8] = {v0.x, v0.y, v0.z, v0.w, v1.x, v1.y, v1.z, v1.w};
    int yy[8], xx[8], pp[8];
    bool val[8];
#pragma unroll
    for (int j = 0; j < 8; ++j) {
        int p = (j < 4) ? (4 * lane + j) : (256 + 4 * lane + (j - 4));
        pp[j] = p;
        yy[j] = p / Wn;
        xx[j] = p - Wn * yy[j];
        val[j] = (j < 4) || has2;
    }

    // ---- Pass A: global max + sum outside the clipped 3x3 priori rect ----
    int ry0 = max(0, py - 1), ry1 = min(Hn - 1, py + 1);
    int rx0 = max(0, px - 1), rx1 = min(Wn - 1, px + 1);
    float m = -INFINITY, s_pri = 0.f;
#pragma unroll
    for (int j = 0; j < 8; ++j) if (val[j]) {
        m = fmaxf(m, c[j]);
        bool inrect = (yy[j] >= ry0) && (yy[j] <= ry1) && (xx[j] >= rx0) && (xx[j] <= rx1);
        if (!inrect) s_pri += c[j];
    }
#pragma unroll
    for (int o = 32; o; o >>= 1) {
        s_pri += __shfl_xor(s_pri, o, 64);
        m = fmaxf(m, __shfl_xor(m, o, 64));
    }
    int n_pri = HWn - (ry1 - ry0 + 1) * (rx1 - rx0 + 1);
    float mean_pri = s_pri / (float)n_pri;

    // ---- Pass B: min squared distance over keep = (cv<=mean_pri && pos!=peak) ----
    int peak_flat = py * Wn + px;
    int dmin = 1 << 30;
#pragma unroll
    for (int j = 0; j < 8; ++j) if (val[j]) {
        if (c[j] <= mean_pri && pp[j] != peak_flat) {
            int dy = yy[j] - py, dx = xx[j] - px;
            int d2 = dy * dy + dx * dx;
            dmin = min(dmin, d2);
        }
    }
#pragma unroll
    for (int o = 32; o; o >>= 1) dmin = min(dmin, __shfl_xor(dmin, o, 64));
    float width = (dmin >= (1 << 30)) ? 100.0f : sqrtf((float)dmin);
    // norm <= clip(width,1.5,4.5) in exact integer form:
    int rad2 = (dmin <= 2) ? 2 : ((dmin >= 21) ? 20 : dmin);

    // ---- Pass C: dynamic clipped-disk exclusion; sum + count of survivors ----
    float s_dyn = 0.f;
    int cnt_ex = 0;
    unsigned exm = 0;
#pragma unroll
    for (int j = 0; j < 8; ++j) if (val[j]) {
        int mdy = (yy[j] == 0) ? py : ((yy[j] == Hn - 1) ? (Hn - 1 - py) : abs(yy[j] - py));
        int mdx = (xx[j] == 0) ? px : ((xx[j] == Wn - 1) ? (Wn - 1 - px) : abs(xx[j] - px));
        if (mdy * mdy + mdx * mdx <= rad2) { cnt_ex++; exm |= (1u << j); }
        else s_dyn += c[j];
    }
#pragma unroll
    for (int o = 32; o; o >>= 1) {
        s_dyn += __shfl_xor(s_dyn, o, 64);
        cnt_ex += __shfl_xor(cnt_ex, o, 64);
    }
    int n = HWn - cnt_ex;
    float mean_s = s_dyn / (float)n;

    // ---- Pass D: variance over survivors ----
    float vs = 0.f;
#pragma unroll
    for (int j = 0; j < 8; ++j) if (val[j] && !((exm >> j) & 1u)) {
        float d = c[j] - mean_s;
        vs += d * d;
    }
#pragma unroll
    for (int o = 32; o; o >>= 1) vs += __shfl_xor(vs, o, 64);
    float var_s = vs / (float)(n - 1);

    if (lane == 0) out[wave] = (m - mean_s) / (var_s * width + 1e-16f);
}

// Normalize each b-row of C=324 psrw values by (mean + 1e-8), in place.
__global__ __launch_bounds__(256) void norm_kernel(float* __restrict__ out, int B)
{
    int gtid = blockIdx.x * 256 + threadIdx.x;
    int wave = gtid >> 6;
    int lane = threadIdx.x & 63;
    if (wave >= B) return;
    float* row = out + (size_t)wave * HWn;
    float4 v0 = reinterpret_cast<float4*>(row)[lane];
    bool has2 = lane < 17;
    float4 v1 = make_float4(0.f, 0.f, 0.f, 0.f);
    if (has2) v1 = reinterpret_cast<float4*>(row)[64 + lane];
    float s = (v0.x + v0.y) + (v0.z + v0.w) + ((v1.x + v1.y) + (v1.z + v1.w));
#pragma unroll
    for (int o = 32; o; o >>= 1) s += __shfl_xor(s, o, 64);
    float denom = s / 324.0f + 1e-8f;
    v0.x /= denom; v0.y /= denom; v0.z /= denom; v0.w /= denom;
    reinterpret_cast<float4*>(row)[lane] = v0;
    if (has2) {
        v1.x /= denom; v1.y /= denom; v1.z /= denom; v1.w /= denom;
        reinterpret_cast<float4*>(row)[64 + lane] = v1;
    }
}

extern "C" void kernel_launch(void* const* d_in, const int* in_sizes, int n_in,
                              void* d_out, int out_size, void* d_ws, size_t ws_size,
                              hipStream_t stream) {
    const float* cv  = (const float*)d_in[0];
    const int* peak  = (const int*)d_in[1];
    // d_in[2]/d_in[3] (mesh_y/mesh_x) are broadcast index grids — recomputed on device.
    float* out = (float*)d_out;

    int BC = in_sizes[1] / 2;       // 256*324 = 82944 tiles
    int blocks1 = (BC + 3) / 4;     // 4 waves per 256-thread block
    psrw_kernel<<<blocks1, 256, 0, stream>>>(cv, peak, out, BC);

    int B = out_size / HWn;         // 256 rows of C=324
    int blocks2 = (B + 3) / 4;
    norm_kernel<<<blocks2, 256, 0, stream>>>(out, B);
}

// Round 2
// 36.950 us; speedup vs baseline: 1.6313x; 1.6313x over previous
//
#include <hip/hip_runtime.h>
#include <math.h>

constexpr int Hn = 18, Wn = 18, HWn = 324;

// Two tiles per wave: lanes 0-31 -> tile 2w, lanes 32-63 -> tile 2w+1.
// Each 32-lane group holds its 324-float tile in 12 register slots
// (3 float4 loads; 3rd valid only for group-lane < 17).
__global__ __launch_bounds__(256) void psrw_kernel(
    const float* __restrict__ cv, const int* __restrict__ peak,
    float* __restrict__ out, int BC)
{
    int gtid = blockIdx.x * 256 + threadIdx.x;
    int wave = gtid >> 6;
    int lane = threadIdx.x & 63;
    int half = lane >> 5;
    int l    = lane & 31;
    int tile = wave * 2 + half;
    if (tile >= BC) return;

    const float* row = cv + (size_t)tile * HWn;
    int2 pkc = ((const int2*)peak)[tile];
    int py = pkc.x, px = pkc.y;
    float pyf = (float)py, pxf = (float)px;

    const float4* rowf4 = (const float4*)row;
    bool have2 = (l < 17);
    float4 v0 = rowf4[l];
    float4 v1 = rowf4[32 + l];
    float4 v2 = have2 ? rowf4[64 + l] : make_float4(0.f, 0.f, 0.f, 0.f);

    float c[12] = {v0.x, v0.y, v0.z, v0.w, v1.x, v1.y, v1.z, v1.w,
                   v2.x, v2.y, v2.z, v2.w};
    float d2[12];

    // Fused setup + Pass A: d2 per slot, global max, priori-rect-excluded sum.
    // Clipping collapses: min-|dy| over the clip preimage == |y-py| always,
    // so rect membership is max(dy^2,dx^2) <= 1 and disk membership d2 <= rad2.
    float m = -INFINITY, s_pri = 0.f;
    float mneg = have2 ? 0.f : -INFINITY;   // invalid 3rd-slot lanes: kill max contrib
#pragma unroll
    for (int j = 0; j < 12; ++j) {
        int f = l + 32 * (j >> 2);
        int p = 4 * f + (j & 3);
        bool valid = (j < 8) || have2;
        if (!valid) p = 100000;             // y huge -> never in rect/disk, d2 ~3e7
        int y = p / 18, x = p - 18 * y;
        float dy = (float)y - pyf;
        float dx = (float)x - pxf;
        float dy2 = dy * dy, dx2 = dx * dx;
        d2[j] = dy2 + dx2;
        float ch = fmaxf(dy2, dx2);
        m = fmaxf(m, (j < 8) ? c[j] : (c[j] + mneg));
        s_pri += (ch <= 1.5f) ? 0.f : c[j]; // invalid slots add c=0
    }
#pragma unroll
    for (int o = 16; o; o >>= 1) {
        s_pri += __shfl_xor(s_pri, o, 64);
        m = fmaxf(m, __shfl_xor(m, o, 64));
    }
    int ry0 = max(0, py - 1), ry1 = min(Hn - 1, py + 1);
    int rx0 = max(0, px - 1), rx1 = min(Wn - 1, px + 1);
    int n_pri = HWn - (ry1 - ry0 + 1) * (rx1 - rx0 + 1);
    float mean_pri = s_pri / (float)n_pri;

    // Pass B: min d2 over keep = (c <= mean_pri) && not-peak (d2 != 0).
    float dmin = 1e30f;
#pragma unroll
    for (int j = 0; j < 12; ++j) {
        bool keep = (c[j] <= mean_pri) && (d2[j] != 0.f);
        dmin = fminf(dmin, keep ? d2[j] : 1e30f);
    }
#pragma unroll
    for (int o = 16; o; o >>= 1) dmin = fminf(dmin, __shfl_xor(dmin, o, 64));

    // A real keep pixel always exists (d2 <= 578); guard the sentinel anyway.
    float width = (dmin > 578.f) ? 100.f : sqrtf(dmin);
    // norm <= clip(width,1.5,4.5) in exact form: n2 <= clip(dmin, 2, 20)
    float rad2 = (dmin <= 2.f) ? 2.f : ((dmin >= 21.f) ? 20.f : dmin);

    // Pass C: survivors (outside dynamic disk): sum, sum-of-squares, disk count.
    float s_dyn = 0.f, ss_dyn = 0.f, cnt_in = 0.f;
#pragma unroll
    for (int j = 0; j < 12; ++j) {
        bool in = (d2[j] <= rad2);          // peak has d2==0 -> always in-disk
        float cm = in ? 0.f : c[j];         // invalid slots: survivor with c=0
        s_dyn += cm;
        ss_dyn = fmaf(cm, cm, ss_dyn);
        cnt_in += in ? 1.f : 0.f;
    }
#pragma unroll
    for (int o = 16; o; o >>= 1) {
        s_dyn  += __shfl_xor(s_dyn, o, 64);
        ss_dyn += __shfl_xor(ss_dyn, o, 64);
        cnt_in += __shfl_xor(cnt_in, o, 64);
    }
    float n = 324.f - cnt_in;
    float mean_s = s_dyn / n;
    float var_s = fmaf(-s_dyn, mean_s, ss_dyn) / (n - 1.f);  // (ss - s^2/n)/(n-1)
    float psrw = (m - mean_s) / fmaf(var_s, width, 1e-16f);
    if (l == 0) out[tile] = psrw;
}

// Normalize each b-row of C=324 psrw values by (mean + 1e-8), in place.
__global__ __launch_bounds__(256) void norm_kernel(float* __restrict__ out, int B)
{
    int gtid = blockIdx.x * 256 + threadIdx.x;
    int wave = gtid >> 6;
    int lane = threadIdx.x & 63;
    if (wave >= B) return;
    float* row = out + (size_t)wave * HWn;
    float4 v0 = reinterpret_cast<float4*>(row)[lane];
    bool has2 = lane < 17;
    float4 v1 = make_float4(0.f, 0.f, 0.f, 0.f);
    if (has2) v1 = reinterpret_cast<float4*>(row)[64 + lane];
    float s = (v0.x + v0.y) + (v0.z + v0.w) + ((v1.x + v1.y) + (v1.z + v1.w));
#pragma unroll
    for (int o = 32; o; o >>= 1) s += __shfl_xor(s, o, 64);
    float denom = s / 324.0f + 1e-8f;
    v0.x /= denom; v0.y /= denom; v0.z /= denom; v0.w /= denom;
    reinterpret_cast<float4*>(row)[lane] = v0;
    if (has2) {
        v1.x /= denom; v1.y /= denom; v1.z /= denom; v1.w /= denom;
        reinterpret_cast<float4*>(row)[64 + lane] = v1;
    }
}

extern "C" void kernel_launch(void* const* d_in, const int* in_sizes, int n_in,
                              void* d_out, int out_size, void* d_ws, size_t ws_size,
                              hipStream_t stream) {
    const float* cv  = (const float*)d_in[0];
    const int* peak  = (const int*)d_in[1];
    // d_in[2]/d_in[3] (mesh_y/mesh_x) are broadcast index grids — recomputed on device.
    float* out = (float*)d_out;

    int BC = in_sizes[1] / 2;               // 82944 tiles
    int waves = (BC + 1) / 2;               // 2 tiles per wave
    int blocks1 = (waves + 3) / 4;          // 4 waves per 256-thread block
    psrw_kernel<<<blocks1, 256, 0, stream>>>(cv, peak, out, BC);

    int B = out_size / HWn;
    int blocks2 = (B + 3) / 4;
    norm_kernel<<<blocks2, 256, 0, stream>>>(out, B);
}

// Round 3
// 28.623 us; speedup vs baseline: 2.1059x; 1.2909x over previous
//
#include <hip/hip_runtime.h>
#include <math.h>

constexpr int Hn = 18, Wn = 18, HWn = 324;

// Four tiles per wave: 16-lane group g handles tile wave*4+g.
// Each group holds its 324-float tile in 21 register slots:
// slots 0-19 from 5 float4 loads (elements 4l+64q+r), slot 20 = tail
// element 320+(l&3), valid only for l<4.
__global__ __launch_bounds__(256) void psrw_kernel(
    const float* __restrict__ cv, const int* __restrict__ peak,
    float* __restrict__ out, int BC)
{
    int gtid = blockIdx.x * 256 + threadIdx.x;
    int wave = gtid >> 6;
    int lane = threadIdx.x & 63;
    int g = lane >> 4;
    int l = lane & 15;
    int tile = wave * 4 + g;
    if (tile >= BC) return;

    const float* row = cv + (size_t)tile * HWn;
    int2 pk = ((const int2*)peak)[tile];
    int py = pk.x, px = pk.y;

    const float4* rf4 = (const float4*)row;
    float4 v0 = rf4[l];
    float4 v1 = rf4[l + 16];
    float4 v2 = rf4[l + 32];
    float4 v3 = rf4[l + 48];
    float4 v4 = rf4[l + 64];
    float tl = row[320 + (l & 3)];
    bool valid20 = (l < 4);

    float c[21] = {v0.x, v0.y, v0.z, v0.w, v1.x, v1.y, v1.z, v1.w,
                   v2.x, v2.y, v2.z, v2.w, v3.x, v3.y, v3.z, v3.w,
                   v4.x, v4.y, v4.z, v4.w, valid20 ? tl : 0.f};
    int d2[21];

    // ---- Fused setup + Pass A ----
    // Integer geometry: y=(p*57)>>10 is exact /18 for p<324; x via mad.
    // Priori 3x3 rect (incl. corners, since sqrt2<1.5) == {d2<=2} on Z^2.
    float m = -INFINITY, s_pri = 0.f;
    int l4 = 4 * l;
#pragma unroll
    for (int j = 0; j < 21; ++j) {
        int p = (j < 20) ? (l4 + 64 * (j >> 2) + (j & 3)) : (320 + (l & 3));
        int y = (p * 57) >> 10;
        int x = p - 18 * y;
        int dy = y - py, dx = x - px;
        int dd = dy * dy + dx * dx;
        if (j == 20) dd = valid20 ? dd : (1 << 20);
        d2[j] = dd;
        m = fmaxf(m, (j == 20 && !valid20) ? -INFINITY : c[j]);
        s_pri += (dd > 2) ? c[j] : 0.f;
    }
#pragma unroll
    for (int o = 8; o; o >>= 1) {
        s_pri += __shfl_xor(s_pri, o, 64);
        m = fmaxf(m, __shfl_xor(m, o, 64));
    }
    int rh = min(Hn - 1, py + 1) - max(0, py - 1) + 1;
    int rw = min(Wn - 1, px + 1) - max(0, px - 1) + 1;
    int n_pri = HWn - rh * rw;
    float mean_pri = s_pri / (float)n_pri;   // IEEE: feeds the keep-compare

    // ---- Pass B: min d2 over keep = (c<=mean_pri) && not-peak (d2!=0) ----
    int dmin = 1 << 20;
#pragma unroll
    for (int j = 0; j < 21; ++j) {
        bool keep = (c[j] <= mean_pri) && (d2[j] != 0);
        dmin = min(dmin, keep ? d2[j] : (1 << 20));
    }
#pragma unroll
    for (int o = 8; o; o >>= 1) dmin = min(dmin, __shfl_xor(dmin, o, 64));

    float width = (dmin >= (1 << 20)) ? 100.f : sqrtf((float)dmin);
    // norm <= clip(width,1.5,4.5)  <=>  d2 <= clip(dmin,2,20) exactly on Z^2
    int rad2 = (dmin <= 2) ? 2 : ((dmin >= 21) ? 20 : dmin);

    // ---- Pass C: survivors outside dynamic disk: sum, sumsq, in-disk count ----
    float s_dyn = 0.f, ss_dyn = 0.f;
    int cnt_in = 0;
#pragma unroll
    for (int j = 0; j < 21; ++j) {
        bool in = (d2[j] <= rad2);           // peak d2==0 -> always in-disk
        float cm = in ? 0.f : c[j];          // invalid slot: survivor, c==0
        s_dyn += cm;
        ss_dyn = fmaf(cm, cm, ss_dyn);
        cnt_in += in ? 1 : 0;
    }
#pragma unroll
    for (int o = 8; o; o >>= 1) {
        s_dyn  += __shfl_xor(s_dyn, o, 64);
        ss_dyn += __shfl_xor(ss_dyn, o, 64);
        cnt_in += __shfl_xor(cnt_in, o, 64);
    }
    float n = (float)(HWn - cnt_in);
    float mean_s = s_dyn / n;
    float var_s = fmaf(-s_dyn, mean_s, ss_dyn) / (n - 1.f);  // (ss - s^2/n)/(n-1)
    float psrw = (m - mean_s) / fmaf(var_s, width, 1e-16f);
    if (l == 0) out[tile] = psrw;
}

// Normalize each b-row of C=324 psrw values by (mean + 1e-8), in place.
__global__ __launch_bounds__(256) void norm_kernel(float* __restrict__ out, int B)
{
    int gtid = blockIdx.x * 256 + threadIdx.x;
    int wave = gtid >> 6;
    int lane = threadIdx.x & 63;
    if (wave >= B) return;
    float* row = out + (size_t)wave * HWn;
    float4 v0 = reinterpret_cast<float4*>(row)[lane];
    bool has2 = lane < 17;
    float4 v1 = make_float4(0.f, 0.f, 0.f, 0.f);
    if (has2) v1 = reinterpret_cast<float4*>(row)[64 + lane];
    float s = (v0.x + v0.y) + (v0.z + v0.w) + ((v1.x + v1.y) + (v1.z + v1.w));
#pragma unroll
    for (int o = 32; o; o >>= 1) s += __shfl_xor(s, o, 64);
    float denom = s / 324.0f + 1e-8f;
    v0.x /= denom; v0.y /= denom; v0.z /= denom; v0.w /= denom;
    reinterpret_cast<float4*>(row)[lane] = v0;
    if (has2) {
        v1.x /= denom; v1.y /= denom; v1.z /= denom; v1.w /= denom;
        reinterpret_cast<float4*>(row)[64 + lane] = v1;
    }
}

extern "C" void kernel_launch(void* const* d_in, const int* in_sizes, int n_in,
                              void* d_out, int out_size, void* d_ws, size_t ws_size,
                              hipStream_t stream) {
    const float* cv  = (const float*)d_in[0];
    const int* peak  = (const int*)d_in[1];
    // d_in[2]/d_in[3] (mesh_y/mesh_x) are broadcast index grids — recomputed on device.
    float* out = (float*)d_out;

    int BC = in_sizes[1] / 2;               // 82944 tiles
    int waves = (BC + 3) / 4;               // 4 tiles per wave
    int blocks1 = (waves + 3) / 4;          // 4 waves per 256-thread block
    psrw_kernel<<<blocks1, 256, 0, stream>>>(cv, peak, out, BC);

    int B = out_size / HWn;
    int blocks2 = (B + 3) / 4;
    norm_kernel<<<blocks2, 256, 0, stream>>>(out, B);
}

// Round 4
// 25.290 us; speedup vs baseline: 2.3834x; 1.1318x over previous
//
#include <hip/hip_runtime.h>
#include <math.h>

constexpr int Hn = 18, Wn = 18, HWn = 324;

// Four tiles per wave; 16-lane group g owns tile wave*4+g.
// Column layout: lane l owns column x=l via slots j=0..17 (element j*18+l),
// plus tails x in {16,17}: slot 18+s -> (y=8s+(l>>1), x=16+(l&1)); slot 20
// valid only for l<4.  dx^2 per lane is constant; dy^2 walks a 2-add
// recurrence -> geometry has no per-slot multiplies.
__global__ __launch_bounds__(256) void psrw_kernel(
    const float* __restrict__ cv, const int* __restrict__ peak,
    float* __restrict__ out, int BC)
{
    int gtid = blockIdx.x * 256 + threadIdx.x;
    int wave = gtid >> 6;
    int lane = threadIdx.x & 63;
    int g = lane >> 4;
    int l = lane & 15;
    int tile = wave * 4 + g;
    if (tile >= BC) return;

    const float* row = cv + (size_t)tile * HWn;
    int2 pk = ((const int2*)peak)[tile];
    int py = pk.x & 31, px = pk.y & 31;   // range-pin: enables mul24/mad24

    const float* colp = row + l;
    float c[21];
#pragma unroll
    for (int j = 0; j < 18; ++j) c[j] = colp[18 * j];   // imm-offset dword loads
    int lh = l >> 1, lb = l & 1;
    const float* tp = row + (lh * 18 + 16 + lb);
    c[18] = tp[0];
    c[19] = tp[144];
    bool v20 = (l < 4);
    c[20] = v20 ? tp[288] : 0.f;          // max flat index 323: always in-tile

    float cpk = row[py * Wn + px];        // peak value (uniform per group)

    // ---- Pass A: max + total sum; rect sum gathered by lanes 0..8 ----
    float m0 = -INFINITY, m1 = -INFINITY, s0 = 0.f, s1 = 0.f;
#pragma unroll
    for (int j = 0; j < 18; j += 2) { m0 = fmaxf(m0, c[j]); s0 += c[j]; }
#pragma unroll
    for (int j = 1; j < 18; j += 2) { m1 = fmaxf(m1, c[j]); s1 += c[j]; }
    m0 = fmaxf(m0, c[18]); s0 += c[18];
    m1 = fmaxf(m1, c[19]); s1 += c[19];
    m0 = fmaxf(m0, v20 ? c[20] : -INFINITY); s0 += c[20];
    float m = fmaxf(m0, m1);
    float s = s0 + s1;

    int ry0 = max(0, py - 1), ry1 = min(Hn - 1, py + 1);
    int rx0 = max(0, px - 1), rx1 = min(Wn - 1, px + 1);
    float rectc = 0.f;
    if (l < 9) {
        int q = (l * 11) >> 5;            // l/3 for l<=8
        int r = l - 3 * q;
        int ry = ry0 + q, rx = rx0 + r;
        if (ry <= ry1 && rx <= rx1) rectc = row[ry * Wn + rx];  // L1 hit
    }
    s -= rectc;                           // fold rect removal into the reduction
#pragma unroll
    for (int o = 8; o; o >>= 1) {
        s += __shfl_xor(s, o, 64);
        m = fmaxf(m, __shfl_xor(m, o, 64));
    }
    int n_pri = HWn - (ry1 - ry0 + 1) * (rx1 - rx0 + 1);
    float mean_pri = s / (float)n_pri;    // IEEE: feeds the keep-compare cliff

    // ---- Pass B: dminb = min over {c<=mean_pri} of (d2-1), unsigned ----
    // ddm1 = dy^2 + (dx^2 - 1); peak (d2=0) wraps to 0xFFFFFFFF -> auto-excluded.
    int dxl = l - px;
    int dx2m1 = dxl * dxl - 1;
    unsigned ddm1[21];
    unsigned A = (unsigned)(py * py + dx2m1);  // dy = 0-py at j=0
    int Bstep = 1 - 2 * py;                    // A += 2*dy+1 per j
    unsigned dminb = 0xFFFFFFFFu;
#pragma unroll
    for (int j = 0; j < 18; ++j) {
        ddm1[j] = A;
        unsigned t = min(dminb, A);
        dminb = (c[j] <= mean_pri) ? t : dminb;
        A += (unsigned)Bstep;
        Bstep += 2;
    }
    int dyt = lh - py;
    int dxt = 16 + lb - px;
    int dxt2m1 = dxt * dxt - 1;
#pragma unroll
    for (int s2 = 0; s2 < 3; ++s2) {
        int dy = dyt + 8 * s2;
        unsigned dd = (unsigned)(dy * dy + dxt2m1);
        if (s2 == 2 && !v20) dd = 0x7FFFFFFFu;   // invalid slot: big, not in-disk
        ddm1[18 + s2] = dd;
        unsigned t = min(dminb, dd);
        dminb = (c[18 + s2] <= mean_pri) ? t : dminb;
    }
#pragma unroll
    for (int o = 8; o; o >>= 1)
        dminb = min(dminb, (unsigned)__shfl_xor((int)dminb, o, 64));

    // width = sqrt(dmin) (sentinel 100); disk test d2<=clip(dmin,2,20) exactly
    float width = (dminb > 577u) ? 100.f
                                 : __builtin_amdgcn_sqrtf((float)(dminb + 1u));
    unsigned rad2m1 = min(max(dminb, 1u), 19u);

    // ---- Pass C: survivors (ddm1 > rad2m1): sum, sumsq, in-disk count ----
    float sd0 = 0.f, sd1 = 0.f, ssd = 0.f;
    int cnt = 0;
#pragma unroll
    for (int j = 0; j < 21; ++j) {
        bool in = (ddm1[j] <= rad2m1);    // peak: huge -> "survivor" (fixed below)
        float cm = in ? 0.f : c[j];
        if (j & 1) sd1 += cm; else sd0 += cm;
        ssd = fmaf(cm, cm, ssd);
        cnt += in ? 1 : 0;
    }
    float sd = sd0 + sd1;
#pragma unroll
    for (int o = 8; o; o >>= 1) {
        sd  += __shfl_xor(sd, o, 64);
        ssd += __shfl_xor(ssd, o, 64);
        cnt += __shfl_xor(cnt, o, 64);
    }
    // peak correction: it is always in-disk (d2=0 <= rad2 since rad2>=2)
    sd -= cpk;
    ssd = fmaf(-cpk, cpk, ssd);
    float n = (float)(HWn - 1 - cnt);
    float mean_s = sd * __builtin_amdgcn_rcpf(n);
    float var_s = fmaf(-sd, mean_s, ssd) * __builtin_amdgcn_rcpf(n - 1.f);
    float psrw = (m - mean_s) * __builtin_amdgcn_rcpf(fmaf(var_s, width, 1e-16f));
    if (l == 0) out[tile] = psrw;
}

// Normalize each b-row of C=324 psrw values by (mean + 1e-8), in place.
__global__ __launch_bounds__(256) void norm_kernel(float* __restrict__ out, int B)
{
    int gtid = blockIdx.x * 256 + threadIdx.x;
    int wave = gtid >> 6;
    int lane = threadIdx.x & 63;
    if (wave >= B) return;
    float* row = out + (size_t)wave * HWn;
    float4 v0 = reinterpret_cast<float4*>(row)[lane];
    bool has2 = lane < 17;
    float4 v1 = make_float4(0.f, 0.f, 0.f, 0.f);
    if (has2) v1 = reinterpret_cast<float4*>(row)[64 + lane];
    float s = (v0.x + v0.y) + (v0.z + v0.w) + ((v1.x + v1.y) + (v1.z + v1.w));
#pragma unroll
    for (int o = 32; o; o >>= 1) s += __shfl_xor(s, o, 64);
    float denom = s / 324.0f + 1e-8f;
    v0.x /= denom; v0.y /= denom; v0.z /= denom; v0.w /= denom;
    reinterpret_cast<float4*>(row)[lane] = v0;
    if (has2) {
        v1.x /= denom; v1.y /= denom; v1.z /= denom; v1.w /= denom;
        reinterpret_cast<float4*>(row)[64 + lane] = v1;
    }
}

extern "C" void kernel_launch(void* const* d_in, const int* in_sizes, int n_in,
                              void* d_out, int out_size, void* d_ws, size_t ws_size,
                              hipStream_t stream) {
    const float* cv  = (const float*)d_in[0];
    const int* peak  = (const int*)d_in[1];
    // d_in[2]/d_in[3] (mesh_y/mesh_x) are broadcast index grids — recomputed on device.
    float* out = (float*)d_out;

    int BC = in_sizes[1] / 2;               // 82944 tiles
    int waves = (BC + 3) / 4;               // 4 tiles per wave
    int blocks1 = (waves + 3) / 4;          // 4 waves per 256-thread block
    psrw_kernel<<<blocks1, 256, 0, stream>>>(cv, peak, out, BC);

    int B = out_size / HWn;
    int blocks2 = (B + 3) / 4;
    norm_kernel<<<blocks2, 256, 0, stream>>>(out, B);
}